// Round 14
// baseline (276.546 us; speedup 1.0000x reference)
//
#include <hip/hip_runtime.h>
#include <cstddef>

// Fixed problem instance (inputs fp32; probe-verified r8)
#define D_FEAT 128
static constexpr int N_NODES = 100000;
static constexpr int N_EDGES = 20000;
static constexpr int N_INC   = 800000;

// r15 two-level counting sort (proven): every scatter window BLOCK-private.
// r17 e2n6 / r18 n2e4 / r19 LDS-staged linear (proven, 276us).
// r20: n2e MLP doubled again — r19 counters (HBM 41%, VALU 9.6%) show the
// 4-chain version is still latency-bound, not BW-bound (BW climbed 2.3->3.3
// TB/s when chains went 1->4). Quarter-split: 2 groups x 4 accumulators =
// 8 independent chains/wave.
static constexpr int NBKT_N  = 196;   // node coarse buckets (512 ids each; 99999>>9=195)
static constexpr int NBKT_E  = 157;   // edge coarse buckets (128 ids each; 19999>>7=156)
static constexpr int NBKT    = NBKT_N + NBKT_E;            // 353
static constexpr int NPBLK   = 256;                        // pass0/pass1 blocks
static constexpr int CHUNK   = N_INC / NPBLK;              // 3125 (exact)
static constexpr int CNT_TOT = NBKT * NPBLK;               // 90368
static constexpr int NBLK3   = CNT_TOT / 256;              // 353 (exact)
static constexpr int LBLK    = (N_NODES + 127) / 128;      // 782 linear blocks

typedef unsigned short u16;
typedef unsigned int   u32;
typedef __attribute__((ext_vector_type(8))) short v8s;     // MFMA A/B frag (8 bf16)
typedef __attribute__((ext_vector_type(4))) float v4f;     // MFMA C/D frag + vec load
typedef __attribute__((ext_vector_type(4))) unsigned short v4u;

// ---------------------------------------------------------------------------
// P0) per-(block,bucket) coarse histogram via LDS (block-private, no global
// atomics). counts layout: [bucket][block]; fully overwritten -> no zeroing.
__global__ __launch_bounds__(256) void pass0_count(
    const int* __restrict__ ni, const int* __restrict__ ei,
    int* __restrict__ counts)
{
    __shared__ int lh[NBKT];
    const int tid = threadIdx.x;
    for (int b = tid; b < NBKT; b += 256) lh[b] = 0;
    __syncthreads();
    const int base = blockIdx.x * CHUNK;
    for (int i = base + tid; i < base + CHUNK; i += 256) {
        atomicAdd(&lh[ni[i] >> 9], 1);
        atomicAdd(&lh[NBKT_N + (ei[i] >> 7)], 1);
    }
    __syncthreads();
    for (int b = tid; b < NBKT; b += 256)
        counts[b * NPBLK + blockIdx.x] = lh[b];
}

// ---------------------------------------------------------------------------
// 2a) per-block exclusive scan IN PLACE (plain, coalesced)
__global__ __launch_bounds__(256) void scanA(
    int* __restrict__ a, int* __restrict__ bsum, int n)
{
    __shared__ int sm[256];
    const int tid = threadIdx.x;
    const int i = blockIdx.x * 256 + tid;
    int v = (i < n) ? a[i] : 0;
    sm[tid] = v;
    __syncthreads();
    #pragma unroll
    for (int d = 1; d < 256; d <<= 1) {
        int t = (tid >= d) ? sm[tid - d] : 0;
        __syncthreads();
        sm[tid] += t;
        __syncthreads();
    }
    if (i < n) a[i] = sm[tid] - v;               // exclusive, block-local
    if (tid == 0) bsum[blockIdx.x] = sm[255];    // block total
}

// 2b) single-block exclusive scan of bsum[n]
__global__ __launch_bounds__(256) void scanB(int* __restrict__ a, int n)
{
    __shared__ int sm[256];
    __shared__ int carry;
    const int tid = threadIdx.x;
    if (tid == 0) carry = 0;
    __syncthreads();
    for (int base = 0; base < n; base += 256) {
        int i = base + tid;
        int v = (i < n) ? a[i] : 0;
        sm[tid] = v;
        __syncthreads();
        #pragma unroll
        for (int d = 1; d < 256; d <<= 1) {
            int t = (tid >= d) ? sm[tid - d] : 0;
            __syncthreads();
            sm[tid] += t;
            __syncthreads();
        }
        int excl = sm[tid] - v + carry;
        int total = sm[255];
        __syncthreads();
        if (tid == 0) carry += total;
        if (i < n) a[i] = excl;
        __syncthreads();
    }
}

// 2c) add block offsets in place
__global__ __launch_bounds__(256) void scanC(
    int* __restrict__ a, const int* __restrict__ bsum, int n)
{
    int i = blockIdx.x * 256 + threadIdx.x;
    if (i < n) a[i] += bsum[blockIdx.x];
}

// ---------------------------------------------------------------------------
// P1) scatter entries into coarse buckets. Each block writes ONLY its own
// sub-segments (cursor init from scanned counts, held in LDS) -> sequential
// block-private writes -> L2 merges to full lines (WRITE ~= payload).
// Entry packs (e,n): e<2^15, n<2^17 -> exactly 32 bits.
__global__ __launch_bounds__(256) void pass1_scatter(
    const int* __restrict__ ni, const int* __restrict__ ei,
    const int* __restrict__ counts, u32* __restrict__ coarse)
{
    __shared__ int cur[NBKT];
    const int tid = threadIdx.x;
    for (int b = tid; b < NBKT; b += 256)
        cur[b] = counts[b * NPBLK + blockIdx.x];
    __syncthreads();
    const int base = blockIdx.x * CHUNK;
    for (int i = base + tid; i < base + CHUNK; i += 256) {
        int n = ni[i], e = ei[i];
        u32 p = ((u32)e << 17) | (u32)n;
        coarse[atomicAdd(&cur[n >> 9], 1)] = p;
        coarse[atomicAdd(&cur[NBKT_N + (e >> 7)], 1)] = p;
    }
}

// ---------------------------------------------------------------------------
// P2n) fine CSR for nodes: one block per coarse bucket (512 nodes). LDS
// hist + 512-wide scan -> ptr_n (degree source); scatter into the bucket's
// global window (block-private -> merges). fineN entry = u16 edge id.
// ptr_n written for all 512 bins; invalid tail bins double as the sentinel
// ptr_n[N_NODES] = N_INC.
__global__ __launch_bounds__(512) void pass2_node(
    const int* __restrict__ counts, const u32* __restrict__ coarse,
    u16* __restrict__ fineN, int* __restrict__ ptr_n)
{
    __shared__ int sm[512];
    __shared__ int cur[512];
    const int tid = threadIdx.x;
    const int B2  = blockIdx.x;
    const int st  = counts[B2 * NPBLK];
    const int en  = counts[(B2 + 1) * NPBLK];  // B2=195 -> edge bucket0 start = 800000
    cur[tid] = 0;
    __syncthreads();
    for (int j = st + tid; j < en; j += 512)
        atomicAdd(&cur[coarse[j] & 511u], 1);
    __syncthreads();
    const int h = cur[tid];
    sm[tid] = h;
    __syncthreads();
    #pragma unroll
    for (int d = 1; d < 512; d <<= 1) {
        int t = (tid >= d) ? sm[tid - d] : 0;
        __syncthreads();
        sm[tid] += t;
        __syncthreads();
    }
    const int start = st + sm[tid] - h;          // exclusive
    ptr_n[B2 * 512 + tid] = start;
    cur[tid] = start;
    __syncthreads();
    for (int j = st + tid; j < en; j += 512) {
        u32 p = coarse[j];
        int pos = atomicAdd(&cur[p & 511u], 1);
        fineN[pos] = (u16)(p >> 17);
    }
}

// P2e) fine CSR for edges: one block per coarse bucket (128 edges).
// fineE entry = u32 node id; ptr_e is fineE-relative. Sentinel
// ptr_e[N_EDGES] = N_INC comes from the last bucket's empty bins.
__global__ __launch_bounds__(512) void pass2_edge(
    const int* __restrict__ counts, const u32* __restrict__ coarse,
    u32* __restrict__ fineE, int* __restrict__ ptr_e)
{
    __shared__ int sm[512];
    __shared__ int cur[512];
    const int tid = threadIdx.x;
    const int B2  = blockIdx.x;
    const int st  = counts[(NBKT_N + B2) * NPBLK];
    const int en  = (B2 + 1 < NBKT_E) ? counts[(NBKT_N + B2 + 1) * NPBLK]
                                      : 2 * N_INC;
    cur[tid] = 0;
    __syncthreads();
    for (int j = st + tid; j < en; j += 512)
        atomicAdd(&cur[(coarse[j] >> 17) & 127u], 1);
    __syncthreads();
    const int h = cur[tid];
    sm[tid] = h;
    __syncthreads();
    #pragma unroll
    for (int d = 1; d < 512; d <<= 1) {
        int t = (tid >= d) ? sm[tid - d] : 0;
        __syncthreads();
        sm[tid] += t;
        __syncthreads();
    }
    const int start = (st - N_INC) + sm[tid] - h;  // fineE-relative
    if (tid < 128) ptr_e[B2 * 128 + tid] = start;
    cur[tid] = start;
    __syncthreads();
    for (int j = st + tid; j < en; j += 512) {
        u32 p = coarse[j];
        fineE[atomicAdd(&cur[(p >> 17) & 127u], 1)] = p & 0x1FFFFu;
    }
}

// ---------------------------------------------------------------------------
// 4a) Dekker split for W only (x split is in-register in linear_mfma).
__global__ __launch_bounds__(256) void split_kernel(
    const float* __restrict__ in, u16* __restrict__ hi, u16* __restrict__ lo, int n4)
{
    for (int i = blockIdx.x * 256 + threadIdx.x; i < n4; i += gridDim.x * 256) {
        v4f v = *(const v4f*)(in + (size_t)i * 4);
        v4u h4, l4;
        #pragma unroll
        for (int c = 0; c < 4; ++c) {
            u32 uv = __float_as_uint(v[c]);
            u32 h  = (uv + 0x7FFFu + ((uv >> 16) & 1u)) & 0xFFFF0000u;  // bf16 RNE
            float r = v[c] - __uint_as_float(h);                        // exact
            u32 ur = __float_as_uint(r);
            u32 l  = ur + 0x7FFFu + ((ur >> 16) & 1u);
            h4[c] = (u16)(h >> 16);
            l4[c] = (u16)(l >> 16);
        }
        *(v4u*)(hi + (size_t)i * 4) = h4;
        *(v4u*)(lo + (size_t)i * 4) = l4;
    }
}

// ---------------------------------------------------------------------------
// 4b) xn = (x @ W^T + b) * rsqrt(deg_n), split-bf16 MFMA. r19 (proven):
// 512-thread blocks (8 waves x 16 rows); Whi/Wlo staged in LDS with XOR
// swizzle byte ^= (row&7)<<4; x fp32 loads + in-register Dekker split.
__global__ __launch_bounds__(512) void linear_mfma(
    const float* __restrict__ x,
    const u16* __restrict__ Whi, const u16* __restrict__ Wlo,
    const float* __restrict__ bias, const int* __restrict__ ptr_n,
    float* __restrict__ xn)
{
    __shared__ u16 sWh[128 * 128];   // 32 KB, swizzled
    __shared__ u16 sWl[128 * 128];   // 32 KB, swizzled
    const int tid = threadIdx.x;
    for (int c = tid; c < 2048; c += 512) {
        const int row = c >> 4;
        const u32 byte = ((u32)c * 16) ^ ((u32)(row & 7) << 4);
        *(v8s*)((char*)sWh + byte) = *(const v8s*)(Whi + (size_t)c * 8);
        *(v8s*)((char*)sWl + byte) = *(const v8s*)(Wlo + (size_t)c * 8);
    }
    __syncthreads();

    const int wave = tid >> 6;
    const int lane = tid & 63;
    const int rowBase = blockIdx.x * 128 + wave * 16;
    if (rowBase >= N_NODES) return;                 // tail waves idle (post-barrier)
    const int m    = lane & 15;
    const int quad = lane >> 4;

    v4f acc[8];
    #pragma unroll
    for (int t = 0; t < 8; ++t) acc[t] = (v4f){0.f, 0.f, 0.f, 0.f};

    #pragma unroll
    for (int ks = 0; ks < 4; ++ks) {
        const int k0 = ks * 32 + quad * 8;
        const float* xp = x + (size_t)(rowBase + m) * D_FEAT + k0;
        const v4f f0 = *(const v4f*)(xp);
        const v4f f1 = *(const v4f*)(xp + 4);
        v8s ah, al;
        #pragma unroll
        for (int c = 0; c < 4; ++c) {
            u32 uv = __float_as_uint(f0[c]);
            u32 h  = (uv + 0x7FFFu + ((uv >> 16) & 1u)) & 0xFFFF0000u;
            float r = f0[c] - __uint_as_float(h);
            u32 ur = __float_as_uint(r);
            u32 l  = ur + 0x7FFFu + ((ur >> 16) & 1u);
            ah[c] = (short)(h >> 16);
            al[c] = (short)(l >> 16);
        }
        #pragma unroll
        for (int c = 0; c < 4; ++c) {
            u32 uv = __float_as_uint(f1[c]);
            u32 h  = (uv + 0x7FFFu + ((uv >> 16) & 1u)) & 0xFFFF0000u;
            float r = f1[c] - __uint_as_float(h);
            u32 ur = __float_as_uint(r);
            u32 l  = ur + 0x7FFFu + ((ur >> 16) & 1u);
            ah[4 + c] = (short)(h >> 16);
            al[4 + c] = (short)(l >> 16);
        }
        #pragma unroll
        for (int t = 0; t < 8; ++t) {
            const int row = t * 16 + m;
            const u32 byte = ((u32)row * 256 + (u32)k0 * 2) ^ ((u32)(row & 7) << 4);
            v8s bh = *(const v8s*)((const char*)sWh + byte);
            v8s bl = *(const v8s*)((const char*)sWl + byte);
            acc[t] = __builtin_amdgcn_mfma_f32_16x16x32_bf16(ah, bh, acc[t], 0, 0, 0);
            acc[t] = __builtin_amdgcn_mfma_f32_16x16x32_bf16(ah, bl, acc[t], 0, 0, 0);
            acc[t] = __builtin_amdgcn_mfma_f32_16x16x32_bf16(al, bh, acc[t], 0, 0, 0);
        }
    }

    const int rq = rowBase + quad * 4;
    const int p0 = ptr_n[rq + 0], p1 = ptr_n[rq + 1], p2 = ptr_n[rq + 2];
    const int p3 = ptr_n[rq + 3], p4 = ptr_n[rq + 4];   // rq+4 <= 100000 (sentinel)
    const int c0 = p1 - p0, c1 = p2 - p1, c2 = p3 - p2, c3 = p4 - p3;
    const float s0 = (c0 > 0) ? rsqrtf((float)c0) : 0.f;
    const float s1 = (c1 > 0) ? rsqrtf((float)c1) : 0.f;
    const float s2 = (c2 > 0) ? rsqrtf((float)c2) : 0.f;
    const float s3 = (c3 > 0) ? rsqrtf((float)c3) : 0.f;

    #pragma unroll
    for (int t = 0; t < 8; ++t) {
        const int col = t * 16 + m;
        const float bv = bias[col];
        float* o = xn + (size_t)rq * D_FEAT + col;
        o[0 * D_FEAT] = (acc[t][0] + bv) * s0;
        o[1 * D_FEAT] = (acc[t][1] + bv) * s1;
        o[2 * D_FEAT] = (acc[t][2] + bv) * s2;
        o[3 * D_FEAT] = (acc[t][3] + bv) * s3;
    }
}

// ---------------------------------------------------------------------------
// 5) per-edge gather, r20: wave = 2 edge-groups x 32 lanes x float4; each
// group's segment split into QUARTERS with independent accumulators ->
// 8 dependent chains/wave (r19 counters: still latency-bound at 4 chains,
// HBM 41%, VALU 9.6%). ef[e,:] = (1/|e|) * sum xn[n,:].
__global__ __launch_bounds__(256) void n2e5(
    const int* __restrict__ ptr_e, const u32* __restrict__ fineE,
    const float* __restrict__ xn, float* __restrict__ ef)
{
    const int wave = threadIdx.x >> 6;
    const int lane = threadIdx.x & 63;
    const int g    = lane >> 5;                             // edge group 0..1
    const int e    = blockIdx.x * 8 + wave * 2 + g;         // 2500*8 == N_EDGES
    const int fo   = (lane & 31) * 4;
    const int st   = ptr_e[e];
    const int en   = ptr_e[e + 1];
    const int len  = en - st;
    const int q    = len >> 2;

    v4f a0 = (v4f){0.f, 0.f, 0.f, 0.f};
    v4f a1 = (v4f){0.f, 0.f, 0.f, 0.f};
    v4f a2 = (v4f){0.f, 0.f, 0.f, 0.f};
    v4f a3 = (v4f){0.f, 0.f, 0.f, 0.f};
    for (int k = 0; k < q; ++k) {
        const int n0 = (int)fineE[st + k];               // 32-lane broadcast
        const int n1 = (int)fineE[st + q + k];
        const int n2 = (int)fineE[st + 2 * q + k];
        const int n3 = (int)fineE[st + 3 * q + k];
        const v4f v0 = *(const v4f*)(xn + (size_t)n0 * D_FEAT + fo);
        const v4f v1 = *(const v4f*)(xn + (size_t)n1 * D_FEAT + fo);
        const v4f v2 = *(const v4f*)(xn + (size_t)n2 * D_FEAT + fo);
        const v4f v3 = *(const v4f*)(xn + (size_t)n3 * D_FEAT + fo);
        a0[0] += v0[0]; a0[1] += v0[1]; a0[2] += v0[2]; a0[3] += v0[3];
        a1[0] += v1[0]; a1[1] += v1[1]; a1[2] += v1[2]; a1[3] += v1[3];
        a2[0] += v2[0]; a2[1] += v2[1]; a2[2] += v2[2]; a2[3] += v2[3];
        a3[0] += v3[0]; a3[1] += v3[1]; a3[2] += v3[2]; a3[3] += v3[3];
    }
    for (int j = st + 4 * q; j < en; ++j) {              // tail (<=3 entries)
        const int n0 = (int)fineE[j];
        const v4f v0 = *(const v4f*)(xn + (size_t)n0 * D_FEAT + fo);
        a0[0] += v0[0]; a0[1] += v0[1]; a0[2] += v0[2]; a0[3] += v0[3];
    }
    const float inv = (len > 0) ? (1.0f / (float)len) : 0.f;
    v4f o;
    #pragma unroll
    for (int c = 0; c < 4; ++c)
        o[c] = (a0[c] + a1[c] + a2[c] + a3[c]) * inv;
    *(v4f*)(ef + (size_t)e * D_FEAT + fo) = o;
}

// ---------------------------------------------------------------------------
// 6) per-node gather + finalize (r17 e2n6, proven): wave = 8 node-groups x
// 8 lanes x float4 over a 32-col slice (slice = blockIdx&3, per-XCD ef
// working set 2.56 MB L2-fits). Serial per group, no butterfly.
__global__ __launch_bounds__(256) void e2n6(
    const int* __restrict__ ptr_n, const u16* __restrict__ fineN,
    const float* __restrict__ ef, float* __restrict__ out)
{
    const int slc  = blockIdx.x & 3;
    const int wave = threadIdx.x >> 6;
    const int lane = threadIdx.x & 63;
    const int g    = lane >> 3;                             // node group 0..7
    const int node = (blockIdx.x >> 2) * 32 + wave * 8 + g; // 3125*32 == N_NODES
    const int col  = slc * 32 + (lane & 7) * 4;
    const int st = ptr_n[node];
    const int en = ptr_n[node + 1];

    v4f a = (v4f){0.f, 0.f, 0.f, 0.f};
    for (int j = st; j < en; ++j) {
        const int e = (int)fineN[j];             // 8-lane broadcast (L1)
        const v4f v = *(const v4f*)(ef + (size_t)e * D_FEAT + col);
        a[0] += v[0]; a[1] += v[1]; a[2] += v[2]; a[3] += v[3];
    }
    const int c = en - st;
    const float s = (c > 0) ? rsqrtf((float)c) : 0.f;
    v4f o;
    #pragma unroll
    for (int q = 0; q < 4; ++q) {
        float r = a[q] * s;
        o[q] = (r > 0.f) ? r : 0.f;
    }
    *(v4f*)(out + (size_t)node * D_FEAT + col) = o;
}

// ---------------------------------------------------------------------------
extern "C" void kernel_launch(void* const* d_in, const int* in_sizes, int n_in,
                              void* d_out, int out_size, void* d_ws, size_t ws_size,
                              hipStream_t stream)
{
    const float* x  = (const float*)d_in[0];   // fp32 (N,128)
    const float* W  = (const float*)d_in[1];   // fp32 (128,128)
    const float* b  = (const float*)d_in[2];   // fp32 (128,)
    const int* ni   = (const int*)d_in[3];     // (800000,) node_idx
    const int* ei   = (const int*)d_in[4];     // (800000,) edge_idx
    float* out = (float*)d_out;                // fp32 (N,128)

    // Workspace ~16 MB (r1 proved >=61.9 MB available).
    // Region A: coarse (6.4 MB) lives FIRST, dies after pass2; ef (10.24 MB)
    // aliases the same base afterwards (written by n2e5).
    char* base = (char*)d_ws;
    u32* coarse = (u32*)base;                                  // 6.4 MB (pre-linear)
    float* ef   = (float*)base;                                // 10.24 MB (post-linear)
    char* p = base + (size_t)N_EDGES * D_FEAT * 4;             // 10.24 MB offset
    int* counts = (int*)p;   p += (size_t)CNT_TOT * 4;         // 362 KB
    int* bsum   = (int*)p;   p += (size_t)((NBLK3 + 7) & ~7) * 4;
    u16* Whi    = (u16*)p;   p += (size_t)D_FEAT * D_FEAT * 2; // 32 KB
    u16* Wlo    = (u16*)p;   p += (size_t)D_FEAT * D_FEAT * 2; // 32 KB
    u16* fineN  = (u16*)p;   p += (size_t)N_INC * 2;           // 1.6 MB
    u32* fineE  = (u32*)p;   p += (size_t)N_INC * 4;           // 3.2 MB
    int* ptr_n  = (int*)p;   p += (size_t)NBKT_N * 512 * 4;    // 401 KB (incl sentinel)
    int* ptr_e  = (int*)p;   p += (size_t)NBKT_E * 128 * 4;    // 80 KB (incl sentinel)
    float* xn   = out;   // xn staged in d_out (linear writes, n2e reads, e2n overwrites)

    // counts fully overwritten by pass0 -> no zeroing pass
    pass0_count<<<NPBLK, 256, 0, stream>>>(ni, ei, counts);

    scanA<<<NBLK3, 256, 0, stream>>>(counts, bsum, CNT_TOT);
    scanB<<<1, 256, 0, stream>>>(bsum, NBLK3);
    scanC<<<NBLK3, 256, 0, stream>>>(counts, bsum, CNT_TOT);

    pass1_scatter<<<NPBLK, 256, 0, stream>>>(ni, ei, counts, coarse);
    pass2_node<<<NBKT_N, 512, 0, stream>>>(counts, coarse, fineN, ptr_n);
    pass2_edge<<<NBKT_E, 512, 0, stream>>>(counts, coarse, fineE, ptr_e);

    split_kernel<<<16, 256, 0, stream>>>(W, Whi, Wlo, D_FEAT * D_FEAT / 4);

    linear_mfma<<<LBLK, 512, 0, stream>>>(x, Whi, Wlo, b, ptr_n, xn);

    n2e5<<<N_EDGES / 8, 256, 0, stream>>>(ptr_e, fineE, xn, ef);

    e2n6<<<(N_NODES / 32) * 4, 256, 0, stream>>>(ptr_n, fineN, ef, out);
}

// Round 15
// 264.002 us; speedup vs baseline: 1.0475x; 1.0475x over previous
//
#include <hip/hip_runtime.h>
#include <cstddef>

// Fixed problem instance (inputs fp32; probe-verified r8)
#define D_FEAT 128
static constexpr int N_NODES = 100000;
static constexpr int N_EDGES = 20000;
static constexpr int N_INC   = 800000;

// r15 two-level counting sort (proven): every scatter window BLOCK-private.
// r17 e2n6 / r18-r20 n2e (8-chain, AT ROOFLINE: 3.4 TB/s random-gather
// ceiling, FETCH 190MB structural) / r19 LDS-staged linear. 276us.
// r21: preprocessing chain was ~110us across 8 launches (~40us intrinsic
// work) -> fuse to 5: [pass0+splitW], scanA, scanD (redundant bsum scan,
// kills single-block scanB), pass1, [pass2 node+edge merged].
static constexpr int NBKT_N  = 196;   // node coarse buckets (512 ids each; 99999>>9=195)
static constexpr int NBKT_E  = 157;   // edge coarse buckets (128 ids each; 19999>>7=156)
static constexpr int NBKT    = NBKT_N + NBKT_E;            // 353
static constexpr int NPBLK   = 256;                        // pass0/pass1 blocks
static constexpr int CHUNK   = N_INC / NPBLK;              // 3125 (exact)
static constexpr int CNT_TOT = NBKT * NPBLK;               // 90368
static constexpr int NBLK3   = CNT_TOT / 256;              // 353 (exact)
static constexpr int LBLK    = (N_NODES + 127) / 128;      // 782 linear blocks

typedef unsigned short u16;
typedef unsigned int   u32;
typedef __attribute__((ext_vector_type(8))) short v8s;     // MFMA A/B frag (8 bf16)
typedef __attribute__((ext_vector_type(4))) float v4f;     // MFMA C/D frag + vec load
typedef __attribute__((ext_vector_type(4))) unsigned short v4u;

// ---------------------------------------------------------------------------
// P0) blocks [0,256): per-(block,bucket) coarse histogram via LDS.
//     blocks [256,272): Dekker split of W (fused; W independent of counts).
// counts layout: [bucket][block]; fully overwritten -> no zeroing.
__global__ __launch_bounds__(256) void pass0_count(
    const int* __restrict__ ni, const int* __restrict__ ei,
    int* __restrict__ counts,
    const float* __restrict__ W, u16* __restrict__ Whi, u16* __restrict__ Wlo)
{
    __shared__ int lh[NBKT];
    const int tid = threadIdx.x;
    if (blockIdx.x < NPBLK) {
        for (int b = tid; b < NBKT; b += 256) lh[b] = 0;
        __syncthreads();
        const int base = blockIdx.x * CHUNK;
        for (int i = base + tid; i < base + CHUNK; i += 256) {
            atomicAdd(&lh[ni[i] >> 9], 1);
            atomicAdd(&lh[NBKT_N + (ei[i] >> 7)], 1);
        }
        __syncthreads();
        for (int b = tid; b < NBKT; b += 256)
            counts[b * NPBLK + blockIdx.x] = lh[b];
    } else {
        // splitW: 4096 v4f chunks over 16 blocks x 256 threads
        const int i = (blockIdx.x - NPBLK) * 256 + tid;     // [0,4096)
        v4f v = *(const v4f*)(W + (size_t)i * 4);
        v4u h4, l4;
        #pragma unroll
        for (int c = 0; c < 4; ++c) {
            u32 uv = __float_as_uint(v[c]);
            u32 h  = (uv + 0x7FFFu + ((uv >> 16) & 1u)) & 0xFFFF0000u;  // bf16 RNE
            float r = v[c] - __uint_as_float(h);                        // exact
            u32 ur = __float_as_uint(r);
            u32 l  = ur + 0x7FFFu + ((ur >> 16) & 1u);
            h4[c] = (u16)(h >> 16);
            l4[c] = (u16)(l >> 16);
        }
        *(v4u*)(Whi + (size_t)i * 4) = h4;
        *(v4u*)(Wlo + (size_t)i * 4) = l4;
    }
}

// ---------------------------------------------------------------------------
// 2a) per-block exclusive scan IN PLACE (plain, coalesced)
__global__ __launch_bounds__(256) void scanA(
    int* __restrict__ a, int* __restrict__ bsum, int n)
{
    __shared__ int sm[256];
    const int tid = threadIdx.x;
    const int i = blockIdx.x * 256 + tid;
    int v = (i < n) ? a[i] : 0;
    sm[tid] = v;
    __syncthreads();
    #pragma unroll
    for (int d = 1; d < 256; d <<= 1) {
        int t = (tid >= d) ? sm[tid - d] : 0;
        __syncthreads();
        sm[tid] += t;
        __syncthreads();
    }
    if (i < n) a[i] = sm[tid] - v;               // exclusive, block-local
    if (tid == 0) bsum[blockIdx.x] = sm[255];    // block total
}

// 2b+2c fused) scanD: every block redundantly scans bsum[353] in LDS
// (L2-hot, 9 rounds) and adds the exclusive block prefix to its 512
// elements. Replaces the single-block scanB + scanC pair.
__global__ __launch_bounds__(512) void scanD(
    int* __restrict__ a, const int* __restrict__ bsum, int n)
{
    __shared__ int sb[512];
    const int tid = threadIdx.x;
    sb[tid] = (tid < NBLK3) ? bsum[tid] : 0;
    __syncthreads();
    #pragma unroll
    for (int d = 1; d < 512; d <<= 1) {
        int t = (tid >= d) ? sb[tid - d] : 0;
        __syncthreads();
        sb[tid] += t;
        __syncthreads();
    }
    const int i = blockIdx.x * 512 + tid;
    if (i < n) {
        const int j = i >> 8;                    // scanA block of element i
        a[i] += (j == 0) ? 0 : sb[j - 1];
    }
}

// ---------------------------------------------------------------------------
// P1) scatter entries into coarse buckets. Each block writes ONLY its own
// sub-segments (cursor init from scanned counts, held in LDS) -> sequential
// block-private writes -> L2 merges to full lines (WRITE ~= payload).
// Entry packs (e,n): e<2^15, n<2^17 -> exactly 32 bits.
__global__ __launch_bounds__(256) void pass1_scatter(
    const int* __restrict__ ni, const int* __restrict__ ei,
    const int* __restrict__ counts, u32* __restrict__ coarse)
{
    __shared__ int cur[NBKT];
    const int tid = threadIdx.x;
    for (int b = tid; b < NBKT; b += 256)
        cur[b] = counts[b * NPBLK + blockIdx.x];
    __syncthreads();
    const int base = blockIdx.x * CHUNK;
    for (int i = base + tid; i < base + CHUNK; i += 256) {
        int n = ni[i], e = ei[i];
        u32 p = ((u32)e << 17) | (u32)n;
        coarse[atomicAdd(&cur[n >> 9], 1)] = p;
        coarse[atomicAdd(&cur[NBKT_N + (e >> 7)], 1)] = p;
    }
}

// ---------------------------------------------------------------------------
// P2) merged fine-CSR build: blocks [0,196) = node buckets (512 nodes each);
// blocks [196,353) = edge buckets (128 edges each). LDS hist + 512-wide
// scan -> ptr (degree source); scatter into the bucket's global window
// (block-private -> merges). fineN = u16 edge id; fineE = u32 node id
// (ptr_e fineE-relative). Sentinels from empty tail bins.
__global__ __launch_bounds__(512) void pass2_both(
    const int* __restrict__ counts, const u32* __restrict__ coarse,
    u16* __restrict__ fineN, int* __restrict__ ptr_n,
    u32* __restrict__ fineE, int* __restrict__ ptr_e)
{
    __shared__ int sm[512];
    __shared__ int cur[512];
    const int tid = threadIdx.x;
    if (blockIdx.x < NBKT_N) {
        const int B2  = blockIdx.x;
        const int st  = counts[B2 * NPBLK];
        const int en  = counts[(B2 + 1) * NPBLK];  // B2=195 -> edge bucket0 start
        cur[tid] = 0;
        __syncthreads();
        for (int j = st + tid; j < en; j += 512)
            atomicAdd(&cur[coarse[j] & 511u], 1);
        __syncthreads();
        const int h = cur[tid];
        sm[tid] = h;
        __syncthreads();
        #pragma unroll
        for (int d = 1; d < 512; d <<= 1) {
            int t = (tid >= d) ? sm[tid - d] : 0;
            __syncthreads();
            sm[tid] += t;
            __syncthreads();
        }
        const int start = st + sm[tid] - h;          // exclusive
        ptr_n[B2 * 512 + tid] = start;
        cur[tid] = start;
        __syncthreads();
        for (int j = st + tid; j < en; j += 512) {
            u32 p = coarse[j];
            int pos = atomicAdd(&cur[p & 511u], 1);
            fineN[pos] = (u16)(p >> 17);
        }
    } else {
        const int B2  = blockIdx.x - NBKT_N;
        const int st  = counts[(NBKT_N + B2) * NPBLK];
        const int en  = (B2 + 1 < NBKT_E) ? counts[(NBKT_N + B2 + 1) * NPBLK]
                                          : 2 * N_INC;
        cur[tid] = 0;
        __syncthreads();
        for (int j = st + tid; j < en; j += 512)
            atomicAdd(&cur[(coarse[j] >> 17) & 127u], 1);
        __syncthreads();
        const int h = cur[tid];
        sm[tid] = h;
        __syncthreads();
        #pragma unroll
        for (int d = 1; d < 512; d <<= 1) {
            int t = (tid >= d) ? sm[tid - d] : 0;
            __syncthreads();
            sm[tid] += t;
            __syncthreads();
        }
        const int start = (st - N_INC) + sm[tid] - h;  // fineE-relative
        if (tid < 128) ptr_e[B2 * 128 + tid] = start;
        cur[tid] = start;
        __syncthreads();
        for (int j = st + tid; j < en; j += 512) {
            u32 p = coarse[j];
            fineE[atomicAdd(&cur[(p >> 17) & 127u], 1)] = p & 0x1FFFFu;
        }
    }
}

// ---------------------------------------------------------------------------
// 4b) xn = (x @ W^T + b) * rsqrt(deg_n), split-bf16 MFMA. r19 (proven):
// 512-thread blocks (8 waves x 16 rows); Whi/Wlo staged in LDS with XOR
// swizzle byte ^= (row&7)<<4; x fp32 loads + in-register Dekker split.
__global__ __launch_bounds__(512) void linear_mfma(
    const float* __restrict__ x,
    const u16* __restrict__ Whi, const u16* __restrict__ Wlo,
    const float* __restrict__ bias, const int* __restrict__ ptr_n,
    float* __restrict__ xn)
{
    __shared__ u16 sWh[128 * 128];   // 32 KB, swizzled
    __shared__ u16 sWl[128 * 128];   // 32 KB, swizzled
    const int tid = threadIdx.x;
    for (int c = tid; c < 2048; c += 512) {
        const int row = c >> 4;
        const u32 byte = ((u32)c * 16) ^ ((u32)(row & 7) << 4);
        *(v8s*)((char*)sWh + byte) = *(const v8s*)(Whi + (size_t)c * 8);
        *(v8s*)((char*)sWl + byte) = *(const v8s*)(Wlo + (size_t)c * 8);
    }
    __syncthreads();

    const int wave = tid >> 6;
    const int lane = tid & 63;
    const int rowBase = blockIdx.x * 128 + wave * 16;
    if (rowBase >= N_NODES) return;                 // tail waves idle (post-barrier)
    const int m    = lane & 15;
    const int quad = lane >> 4;

    v4f acc[8];
    #pragma unroll
    for (int t = 0; t < 8; ++t) acc[t] = (v4f){0.f, 0.f, 0.f, 0.f};

    #pragma unroll
    for (int ks = 0; ks < 4; ++ks) {
        const int k0 = ks * 32 + quad * 8;
        const float* xp = x + (size_t)(rowBase + m) * D_FEAT + k0;
        const v4f f0 = *(const v4f*)(xp);
        const v4f f1 = *(const v4f*)(xp + 4);
        v8s ah, al;
        #pragma unroll
        for (int c = 0; c < 4; ++c) {
            u32 uv = __float_as_uint(f0[c]);
            u32 h  = (uv + 0x7FFFu + ((uv >> 16) & 1u)) & 0xFFFF0000u;
            float r = f0[c] - __uint_as_float(h);
            u32 ur = __float_as_uint(r);
            u32 l  = ur + 0x7FFFu + ((ur >> 16) & 1u);
            ah[c] = (short)(h >> 16);
            al[c] = (short)(l >> 16);
        }
        #pragma unroll
        for (int c = 0; c < 4; ++c) {
            u32 uv = __float_as_uint(f1[c]);
            u32 h  = (uv + 0x7FFFu + ((uv >> 16) & 1u)) & 0xFFFF0000u;
            float r = f1[c] - __uint_as_float(h);
            u32 ur = __float_as_uint(r);
            u32 l  = ur + 0x7FFFu + ((ur >> 16) & 1u);
            ah[4 + c] = (short)(h >> 16);
            al[4 + c] = (short)(l >> 16);
        }
        #pragma unroll
        for (int t = 0; t < 8; ++t) {
            const int row = t * 16 + m;
            const u32 byte = ((u32)row * 256 + (u32)k0 * 2) ^ ((u32)(row & 7) << 4);
            v8s bh = *(const v8s*)((const char*)sWh + byte);
            v8s bl = *(const v8s*)((const char*)sWl + byte);
            acc[t] = __builtin_amdgcn_mfma_f32_16x16x32_bf16(ah, bh, acc[t], 0, 0, 0);
            acc[t] = __builtin_amdgcn_mfma_f32_16x16x32_bf16(ah, bl, acc[t], 0, 0, 0);
            acc[t] = __builtin_amdgcn_mfma_f32_16x16x32_bf16(al, bh, acc[t], 0, 0, 0);
        }
    }

    const int rq = rowBase + quad * 4;
    const int p0 = ptr_n[rq + 0], p1 = ptr_n[rq + 1], p2 = ptr_n[rq + 2];
    const int p3 = ptr_n[rq + 3], p4 = ptr_n[rq + 4];   // rq+4 <= 100000 (sentinel)
    const int c0 = p1 - p0, c1 = p2 - p1, c2 = p3 - p2, c3 = p4 - p3;
    const float s0 = (c0 > 0) ? rsqrtf((float)c0) : 0.f;
    const float s1 = (c1 > 0) ? rsqrtf((float)c1) : 0.f;
    const float s2 = (c2 > 0) ? rsqrtf((float)c2) : 0.f;
    const float s3 = (c3 > 0) ? rsqrtf((float)c3) : 0.f;

    #pragma unroll
    for (int t = 0; t < 8; ++t) {
        const int col = t * 16 + m;
        const float bv = bias[col];
        float* o = xn + (size_t)rq * D_FEAT + col;
        o[0 * D_FEAT] = (acc[t][0] + bv) * s0;
        o[1 * D_FEAT] = (acc[t][1] + bv) * s1;
        o[2 * D_FEAT] = (acc[t][2] + bv) * s2;
        o[3 * D_FEAT] = (acc[t][3] + bv) * s3;
    }
}

// ---------------------------------------------------------------------------
// 5) per-edge gather (r20 n2e5, AT ROOFLINE ~3.4 TB/s random gather):
// wave = 2 edge-groups x 32 lanes x float4; quarter-split accumulators ->
// 8 independent chains/wave. ef[e,:] = (1/|e|) * sum xn[n,:].
__global__ __launch_bounds__(256) void n2e5(
    const int* __restrict__ ptr_e, const u32* __restrict__ fineE,
    const float* __restrict__ xn, float* __restrict__ ef)
{
    const int wave = threadIdx.x >> 6;
    const int lane = threadIdx.x & 63;
    const int g    = lane >> 5;                             // edge group 0..1
    const int e    = blockIdx.x * 8 + wave * 2 + g;         // 2500*8 == N_EDGES
    const int fo   = (lane & 31) * 4;
    const int st   = ptr_e[e];
    const int en   = ptr_e[e + 1];
    const int len  = en - st;
    const int q    = len >> 2;

    v4f a0 = (v4f){0.f, 0.f, 0.f, 0.f};
    v4f a1 = (v4f){0.f, 0.f, 0.f, 0.f};
    v4f a2 = (v4f){0.f, 0.f, 0.f, 0.f};
    v4f a3 = (v4f){0.f, 0.f, 0.f, 0.f};
    for (int k = 0; k < q; ++k) {
        const int n0 = (int)fineE[st + k];               // 32-lane broadcast
        const int n1 = (int)fineE[st + q + k];
        const int n2 = (int)fineE[st + 2 * q + k];
        const int n3 = (int)fineE[st + 3 * q + k];
        const v4f v0 = *(const v4f*)(xn + (size_t)n0 * D_FEAT + fo);
        const v4f v1 = *(const v4f*)(xn + (size_t)n1 * D_FEAT + fo);
        const v4f v2 = *(const v4f*)(xn + (size_t)n2 * D_FEAT + fo);
        const v4f v3 = *(const v4f*)(xn + (size_t)n3 * D_FEAT + fo);
        a0[0] += v0[0]; a0[1] += v0[1]; a0[2] += v0[2]; a0[3] += v0[3];
        a1[0] += v1[0]; a1[1] += v1[1]; a1[2] += v1[2]; a1[3] += v1[3];
        a2[0] += v2[0]; a2[1] += v2[1]; a2[2] += v2[2]; a2[3] += v2[3];
        a3[0] += v3[0]; a3[1] += v3[1]; a3[2] += v3[2]; a3[3] += v3[3];
    }
    for (int j = st + 4 * q; j < en; ++j) {              // tail (<=3 entries)
        const int n0 = (int)fineE[j];
        const v4f v0 = *(const v4f*)(xn + (size_t)n0 * D_FEAT + fo);
        a0[0] += v0[0]; a0[1] += v0[1]; a0[2] += v0[2]; a0[3] += v0[3];
    }
    const float inv = (len > 0) ? (1.0f / (float)len) : 0.f;
    v4f o;
    #pragma unroll
    for (int c = 0; c < 4; ++c)
        o[c] = (a0[c] + a1[c] + a2[c] + a3[c]) * inv;
    *(v4f*)(ef + (size_t)e * D_FEAT + fo) = o;
}

// ---------------------------------------------------------------------------
// 6) per-node gather + finalize (r17 e2n6, proven): wave = 8 node-groups x
// 8 lanes x float4 over a 32-col slice (slice = blockIdx&3, per-XCD ef
// working set 2.56 MB L2-fits). Serial per group, no butterfly.
__global__ __launch_bounds__(256) void e2n6(
    const int* __restrict__ ptr_n, const u16* __restrict__ fineN,
    const float* __restrict__ ef, float* __restrict__ out)
{
    const int slc  = blockIdx.x & 3;
    const int wave = threadIdx.x >> 6;
    const int lane = threadIdx.x & 63;
    const int g    = lane >> 3;                             // node group 0..7
    const int node = (blockIdx.x >> 2) * 32 + wave * 8 + g; // 3125*32 == N_NODES
    const int col  = slc * 32 + (lane & 7) * 4;
    const int st = ptr_n[node];
    const int en = ptr_n[node + 1];

    v4f a = (v4f){0.f, 0.f, 0.f, 0.f};
    for (int j = st; j < en; ++j) {
        const int e = (int)fineN[j];             // 8-lane broadcast (L1)
        const v4f v = *(const v4f*)(ef + (size_t)e * D_FEAT + col);
        a[0] += v[0]; a[1] += v[1]; a[2] += v[2]; a[3] += v[3];
    }
    const int c = en - st;
    const float s = (c > 0) ? rsqrtf((float)c) : 0.f;
    v4f o;
    #pragma unroll
    for (int q = 0; q < 4; ++q) {
        float r = a[q] * s;
        o[q] = (r > 0.f) ? r : 0.f;
    }
    *(v4f*)(out + (size_t)node * D_FEAT + col) = o;
}

// ---------------------------------------------------------------------------
extern "C" void kernel_launch(void* const* d_in, const int* in_sizes, int n_in,
                              void* d_out, int out_size, void* d_ws, size_t ws_size,
                              hipStream_t stream)
{
    const float* x  = (const float*)d_in[0];   // fp32 (N,128)
    const float* W  = (const float*)d_in[1];   // fp32 (128,128)
    const float* b  = (const float*)d_in[2];   // fp32 (128,)
    const int* ni   = (const int*)d_in[3];     // (800000,) node_idx
    const int* ei   = (const int*)d_in[4];     // (800000,) edge_idx
    float* out = (float*)d_out;                // fp32 (N,128)

    // Workspace ~16 MB (r1 proved >=61.9 MB available).
    // Region A: coarse (6.4 MB) lives FIRST, dies after pass2; ef (10.24 MB)
    // aliases the same base afterwards (written by n2e5).
    char* base = (char*)d_ws;
    u32* coarse = (u32*)base;                                  // 6.4 MB (pre-linear)
    float* ef   = (float*)base;                                // 10.24 MB (post-linear)
    char* p = base + (size_t)N_EDGES * D_FEAT * 4;             // 10.24 MB offset
    int* counts = (int*)p;   p += (size_t)CNT_TOT * 4;         // 362 KB
    int* bsum   = (int*)p;   p += (size_t)((NBLK3 + 7) & ~7) * 4;
    u16* Whi    = (u16*)p;   p += (size_t)D_FEAT * D_FEAT * 2; // 32 KB
    u16* Wlo    = (u16*)p;   p += (size_t)D_FEAT * D_FEAT * 2; // 32 KB
    u16* fineN  = (u16*)p;   p += (size_t)N_INC * 2;           // 1.6 MB
    u32* fineE  = (u32*)p;   p += (size_t)N_INC * 4;           // 3.2 MB
    int* ptr_n  = (int*)p;   p += (size_t)NBKT_N * 512 * 4;    // 401 KB (incl sentinel)
    int* ptr_e  = (int*)p;   p += (size_t)NBKT_E * 128 * 4;    // 80 KB (incl sentinel)
    float* xn   = out;   // xn staged in d_out (linear writes, n2e reads, e2n overwrites)

    // 5-launch preprocessing (was 8): counts fully overwritten -> no zeroing
    pass0_count<<<NPBLK + 16, 256, 0, stream>>>(ni, ei, counts, W, Whi, Wlo);

    scanA<<<NBLK3, 256, 0, stream>>>(counts, bsum, CNT_TOT);
    scanD<<<(CNT_TOT + 511) / 512, 512, 0, stream>>>(counts, bsum, CNT_TOT);

    pass1_scatter<<<NPBLK, 256, 0, stream>>>(ni, ei, counts, coarse);
    pass2_both<<<NBKT, 512, 0, stream>>>(counts, coarse, fineN, ptr_n, fineE, ptr_e);

    linear_mfma<<<LBLK, 512, 0, stream>>>(x, Whi, Wlo, b, ptr_n, xn);

    n2e5<<<N_EDGES / 8, 256, 0, stream>>>(ptr_e, fineE, xn, ef);

    e2n6<<<(N_NODES / 32) * 4, 256, 0, stream>>>(ptr_n, fineN, ef, out);
}